// Round 6
// baseline (85.307 us; speedup 1.0000x reference)
//
#include <hip/hip_runtime.h>
#include <math.h>

#define LOG2E 1.4426950408889634f
#define E1 0.36787944117144233f

typedef __attribute__((ext_vector_type(8))) short short8;   // 8 bf16 (4 VGPR)
typedef __attribute__((ext_vector_type(4))) float f32x4;    // MFMA C/D
typedef __attribute__((ext_vector_type(2))) float f32x2;    // packed-f32 pair

__device__ __forceinline__ float fexp2(float x) { return __builtin_amdgcn_exp2f(x); }

// 21 Gaussian kernels for 2 sims -> acc[21] (f32x2), DEFERRED normalization:
//   g_{9+j}(s) = gc * v^j * e^{-j^2/2},  v = e^{10s+0.5}, gc = e^{-50(s+0.05)^2}
// We accumulate p_j = gc*v^j (pure geometric, 2 packed ops per k) and apply
// c_j = e^{-j^2/2} once at the fold. Overflow-safe: with |s|<=1.1,
// max p = e^{50}, max acc = 512*e^{50} << f32 max. Verified algebraically:
// c_1*gc*v   = exp(-50(s-0.05)^2) = g_10; c_1*gc/v = exp(-50(s+0.15)^2) = g_8.
__device__ __forceinline__ void kern21(f32x2 s, f32x2* acc)
{
    s.x = __builtin_amdgcn_fmed3f(s.x, -1.1f, 1.1f);
    s.y = __builtin_amdgcn_fmed3f(s.y, -1.1f, 1.1f);

    f32x2 va = s * 14.426950408889634f + 0.7213475204444817f;  // log2(e)*(10s+0.5)
    f32x2 v, vi, gc;
    v.x  = fexp2(va.x);  v.y  = fexp2(va.y);
    vi.x = __builtin_amdgcn_rcpf(v.x);
    vi.y = __builtin_amdgcn_rcpf(v.y);
    f32x2 t9 = s + 0.05f;
    f32x2 ga = (t9 * t9) * -72.13475204444817f;                // -50/ln2
    gc.x = fexp2(ga.x);  gc.y = fexp2(ga.y);

    f32x2 p = gc;
    acc[9] += p;
    #pragma unroll
    for (int k = 10; k <= 19; ++k) { p *= v; acc[k] += p; }    // up: j=1..10
    f32x2 q = gc;
    #pragma unroll
    for (int k = 8; k >= 0; --k) { q *= vi; acc[k] += q; }     // down: j=1..9
    // exact kernel (mu=1, sigma=0.001): wave-uniform skip (~0.1% taken)
    if (__any(fmaxf(s.x, s.y) > 0.995f)) {
        f32x2 te = s - 1.0f;
        f32x2 ea = (te * te) * -721347.5204444817f;
        f32x2 ge; ge.x = fexp2(ea.x); ge.y = fexp2(ea.y);
        acc[20] += ge;
    }
}

// One doc chunk step: 6 MFMAs (hi/lo 3-term split) + 2x kern21.
__device__ __forceinline__ void doc_step(
    uint4 h0, uint4 h1, uint4 l0, uint4 l1,
    short8 Bh0, short8 Bh1, short8 Bl0, short8 Bl1, f32x2* acc)
{
    short8 Ah0 = __builtin_bit_cast(short8, h0);
    short8 Ah1 = __builtin_bit_cast(short8, h1);
    short8 Al0 = __builtin_bit_cast(short8, l0);
    short8 Al1 = __builtin_bit_cast(short8, l1);

    f32x4 C = {0.f, 0.f, 0.f, 0.f};
    C = __builtin_amdgcn_mfma_f32_16x16x32_bf16(Ah0, Bh0, C, 0, 0, 0);
    C = __builtin_amdgcn_mfma_f32_16x16x32_bf16(Ah1, Bh1, C, 0, 0, 0);
    C = __builtin_amdgcn_mfma_f32_16x16x32_bf16(Ah0, Bl0, C, 0, 0, 0);
    C = __builtin_amdgcn_mfma_f32_16x16x32_bf16(Ah1, Bl1, C, 0, 0, 0);
    C = __builtin_amdgcn_mfma_f32_16x16x32_bf16(Al0, Bh0, C, 0, 0, 0);
    C = __builtin_amdgcn_mfma_f32_16x16x32_bf16(Al1, Bh1, C, 0, 0, 0);

    f32x2 a01 = {C[0], C[1]};
    f32x2 a23 = {C[2], C[3]};
    kern21(a01, acc);
    kern21(a23, acc);
}

// ---- prep: normalize + bf16 hi/lo split every vocab row into ws ----
// layout: wse[tok*16 + 0..7] = hi chunks, wse[tok*16 + 8..15] = lo chunks
__global__ __launch_bounds__(256) void knrm_prep_kernel(
    const float* __restrict__ emb, uint4* __restrict__ wse, int vocab)
{
    const int tid = threadIdx.x;
    const int row = blockIdx.x * 32 + (tid >> 3);
    const int cb  = tid & 7;
    if (row >= vocab) return;   // whole 8-lane group exits together

    const float* src = emb + (size_t)row * 50;
    float v[8];
    float ss = 0.f;
    #pragma unroll
    for (int p = 0; p < 4; ++p) {
        int e = cb * 8 + 2 * p;
        float2 t;
        if (e + 2 <= 50) t = *(const float2*)(src + e);
        else             t = make_float2(0.f, 0.f);
        v[2*p]   = t.x;
        v[2*p+1] = t.y;
        ss = fmaf(t.x, t.x, fmaf(t.y, t.y, ss));
    }
    ss += __shfl_xor(ss, 1, 64);
    ss += __shfl_xor(ss, 2, 64);
    ss += __shfl_xor(ss, 4, 64);
    float rn = __builtin_amdgcn_rsqf(ss);

    unsigned hw[4], lw[4];
    #pragma unroll
    for (int p = 0; p < 4; ++p) {
        float a = v[2*p]   * rn;
        float b = v[2*p+1] * rn;
        unsigned ha = __float_as_uint(a) & 0xFFFF0000u;
        unsigned hb = __float_as_uint(b) & 0xFFFF0000u;
        float la = a - __uint_as_float(ha);
        float lb = b - __uint_as_float(hb);
        hw[p] = (ha >> 16) | hb;
        lw[p] = (__float_as_uint(la) >> 16) | (__float_as_uint(lb) & 0xFFFF0000u);
    }
    wse[(size_t)row * 16 + cb]     = make_uint4(hw[0], hw[1], hw[2], hw[3]);
    wse[(size_t)row * 16 + 8 + cb] = make_uint4(lw[0], lw[1], lw[2], lw[3]);
}

// ==== main pass kernel: NO doc LDS, NO main-loop barriers ====
// One block = one (batch, pass). 4 waves: wave = (qtile<<1)|dtile.
// Each lane loads its MFMA A/B fragments DIRECTLY from wse (L3-resident,
// 25.6 MB): 4 lanes (g=0..3) of a row cover one 64B line -> fully coalesced.
// Register double-buffer on A, depth-2 token-index prefetch.
__global__ __launch_bounds__(256, 4) void knrm_pass_pre(
    const int* __restrict__ q1, const int* __restrict__ d1,
    const int* __restrict__ q2, const int* __restrict__ d2,
    const uint4* __restrict__ wse, const float* __restrict__ mlp_w,
    float* __restrict__ ws_logit)
{
    __shared__ float Swk[4][21][16];
    __shared__ float wred[4];

    const int tid  = threadIdx.x;
    const int bx   = blockIdx.x;
    const int b    = bx >> 1;
    const int lane = tid & 63;
    const int wave = tid >> 6;
    const int g    = lane >> 4;          // k-group 0..3

    const int* qidx = ((bx & 1) ? q2 : q1) + b * 32;
    const int* didx = ((bx & 1) ? d2 : d1) + b * 512;

    // ---- B fragments straight from global (once) ----
    const int qrow = (wave >> 1) * 16 + (lane & 15);
    const uint4* qb = wse + (size_t)qidx[qrow] * 16;
    short8 Bh0 = __builtin_bit_cast(short8, qb[g]);
    short8 Bh1 = __builtin_bit_cast(short8, qb[4 + g]);
    short8 Bl0 = __builtin_bit_cast(short8, qb[8 + g]);
    short8 Bl1 = __builtin_bit_cast(short8, qb[12 + g]);

    f32x2 acc2[21];
    #pragma unroll
    for (int k = 0; k < 21; ++k) acc2[k] = (f32x2){0.f, 0.f};

    const int arow = (wave & 1) * 16 + (lane & 15);

    // prologue: A regs <- chunk 0; tokN = idx(chunk 1)
    {
        int tok0 = didx[arow];
        const uint4* a0 = wse + (size_t)tok0 * 16;
        // fallthrough into loop with A = chunk0
        uint4 Ah0 = a0[g], Ah1 = a0[4 + g], Al0 = a0[8 + g], Al1 = a0[12 + g];
        int tokN = didx[32 + arow];

        for (int c = 0; c < 16; c += 2) {
            // issue loads for chunk c+1 (NA regs)
            const uint4* an = wse + (size_t)tokN * 16;
            uint4 NAh0 = an[g], NAh1 = an[4 + g], NAl0 = an[8 + g], NAl1 = an[12 + g];
            int cn = (c + 2 < 16) ? (c + 2) : 15;       // clamp (tail dummy)
            tokN = didx[cn * 32 + arow];

            doc_step(Ah0, Ah1, Al0, Al1, Bh0, Bh1, Bl0, Bl1, acc2);   // chunk c

            // issue loads for chunk c+2 (A regs; tail iteration re-reads 15, discarded)
            const uint4* an2 = wse + (size_t)tokN * 16;
            Ah0 = an2[g]; Ah1 = an2[4 + g]; Al0 = an2[8 + g]; Al1 = an2[12 + g];
            int cn2 = (c + 3 < 16) ? (c + 3) : 15;
            tokN = didx[cn2 * 32 + arow];

            doc_step(NAh0, NAh1, NAl0, NAl1, Bh0, Bh1, Bl0, Bl1, acc2); // chunk c+1
        }
    }

    // ---- fold packed pair, then the 4 doc-row groups ----
    float acc[21];
    #pragma unroll
    for (int k = 0; k < 21; ++k) {
        float v = acc2[k].x + acc2[k].y;
        v += __shfl_xor(v, 16, 64);
        v += __shfl_xor(v, 32, 64);
        acc[k] = v;
    }
    if (lane < 16) {
        #pragma unroll
        for (int k = 0; k < 21; ++k) Swk[wave][k][lane] = acc[k];
    }
    __syncthreads();

    // ---- log1p + deferred c_j scale + kernel weights + block reduction ----
    float local = 0.f;
    for (int p = tid; p < 21 * 32; p += 256) {
        int k = p >> 5, q = p & 31;
        int wp = (q >> 4) * 2;
        float S = Swk[wp][k][q & 15] + Swk[wp + 1][k][q & 15];
        float j = (float)(k - 9);
        float scale = (k < 20) ? fexp2(-0.7213475204444817f * j * j) : 1.0f;
        local += mlp_w[k] * log1pf(S * scale);
    }
    #pragma unroll
    for (int off = 1; off < 64; off <<= 1) local += __shfl_xor(local, off, 64);
    if (lane == 0) wred[wave] = local;
    __syncthreads();
    if (tid == 0)
        ws_logit[bx] = wred[0] + wred[1] + wred[2] + wred[3];  // bias cancels in l1-l2
}

// ==== fallback (ws too small): R2-proven in-kernel staging via LDS ====
__device__ __forceinline__ void stage_row_chunk(
    const float* __restrict__ emb, int tok, int row, int cb,
    uint4* __restrict__ hmat, uint4* __restrict__ lmat)
{
    const float* src = emb + (size_t)tok * 50;
    float v[8];
    float ss = 0.f;
    #pragma unroll
    for (int p = 0; p < 4; ++p) {
        int e = cb * 8 + 2 * p;
        float2 t;
        if (e + 2 <= 50) t = *(const float2*)(src + e);
        else             t = make_float2(0.f, 0.f);
        v[2*p]   = t.x;
        v[2*p+1] = t.y;
        ss = fmaf(t.x, t.x, fmaf(t.y, t.y, ss));
    }
    ss += __shfl_xor(ss, 1, 64);
    ss += __shfl_xor(ss, 2, 64);
    ss += __shfl_xor(ss, 4, 64);
    float rn = __builtin_amdgcn_rsqf(ss);

    unsigned hw[4], lw[4];
    #pragma unroll
    for (int p = 0; p < 4; ++p) {
        float a = v[2*p]   * rn;
        float b = v[2*p+1] * rn;
        unsigned ha = __float_as_uint(a) & 0xFFFF0000u;
        unsigned hb = __float_as_uint(b) & 0xFFFF0000u;
        float la = a - __uint_as_float(ha);
        float lb = b - __uint_as_float(hb);
        hw[p] = (ha >> 16) | hb;
        lw[p] = (__float_as_uint(la) >> 16) | (__float_as_uint(lb) & 0xFFFF0000u);
    }
    int cidx = cb ^ (row & 7);
    hmat[row * 8 + cidx] = make_uint4(hw[0], hw[1], hw[2], hw[3]);
    lmat[row * 8 + cidx] = make_uint4(lw[0], lw[1], lw[2], lw[3]);
}

__device__ __forceinline__ short8 frag_ld(const uint4* mat, int row, int chunk)
{
    return __builtin_bit_cast(short8, mat[row * 8 + (chunk ^ (row & 7))]);
}

__global__ __launch_bounds__(256, 4) void knrm_pass_fb(
    const int* __restrict__ q1, const int* __restrict__ d1,
    const int* __restrict__ q2, const int* __restrict__ d2,
    const float* __restrict__ emb, const float* __restrict__ mlp_w,
    float* __restrict__ ws_logit)
{
    __shared__ uint4 qh4[32 * 8], ql4[32 * 8];
    __shared__ uint4 dh4[32 * 8], dl4[32 * 8];
    __shared__ float Swk[4][21][16];
    __shared__ float wred[4];

    const int tid  = threadIdx.x;
    const int bx   = blockIdx.x;
    const int b    = bx >> 1;
    const int lane = tid & 63;
    const int wave = tid >> 6;
    const int g    = lane >> 4;

    const int* qidx = ((bx & 1) ? q2 : q1) + b * 32;
    const int* didx = ((bx & 1) ? d2 : d1) + b * 512;

    const int srow = tid >> 3;
    const int scb  = tid & 7;

    stage_row_chunk(emb, qidx[srow], srow, scb, qh4, ql4);
    __syncthreads();

    const int qrow = (wave >> 1) * 16 + (lane & 15);
    short8 Bh0 = frag_ld(qh4, qrow, g);
    short8 Bh1 = frag_ld(qh4, qrow, 4 + g);
    short8 Bl0 = frag_ld(ql4, qrow, g);
    short8 Bl1 = frag_ld(ql4, qrow, 4 + g);

    f32x2 acc2[21];
    #pragma unroll
    for (int k = 0; k < 21; ++k) acc2[k] = (f32x2){0.f, 0.f};

    const int arow = (wave & 1) * 16 + (lane & 15);

    for (int c = 0; c < 16; ++c) {
        if (c) __syncthreads();
        stage_row_chunk(emb, didx[c * 32 + srow], srow, scb, dh4, dl4);
        __syncthreads();

        uint4 h0 = __builtin_bit_cast(uint4, frag_ld(dh4, arow, g));
        uint4 h1 = __builtin_bit_cast(uint4, frag_ld(dh4, arow, 4 + g));
        uint4 l0 = __builtin_bit_cast(uint4, frag_ld(dl4, arow, g));
        uint4 l1 = __builtin_bit_cast(uint4, frag_ld(dl4, arow, 4 + g));
        doc_step(h0, h1, l0, l1, Bh0, Bh1, Bl0, Bl1, acc2);
    }
    __syncthreads();

    float acc[21];
    #pragma unroll
    for (int k = 0; k < 21; ++k) {
        float v = acc2[k].x + acc2[k].y;
        v += __shfl_xor(v, 16, 64);
        v += __shfl_xor(v, 32, 64);
        acc[k] = v;
    }
    if (lane < 16) {
        #pragma unroll
        for (int k = 0; k < 21; ++k) Swk[wave][k][lane] = acc[k];
    }
    __syncthreads();

    float local = 0.f;
    for (int p = tid; p < 21 * 32; p += 256) {
        int k = p >> 5, q = p & 31;
        int wp = (q >> 4) * 2;
        float S = Swk[wp][k][q & 15] + Swk[wp + 1][k][q & 15];
        float j = (float)(k - 9);
        float scale = (k < 20) ? fexp2(-0.7213475204444817f * j * j) : 1.0f;
        local += mlp_w[k] * log1pf(S * scale);
    }
    #pragma unroll
    for (int off = 1; off < 64; off <<= 1) local += __shfl_xor(local, off, 64);
    if (lane == 0) wred[wave] = local;
    __syncthreads();
    if (tid == 0)
        ws_logit[bx] = wred[0] + wred[1] + wred[2] + wred[3];
}

__global__ void knrm_final_kernel(const float* __restrict__ ws_logit,
                                  float* __restrict__ out, int B)
{
    int i = blockIdx.x * 256 + threadIdx.x;
    if (i < B) {
        float x = ws_logit[2 * i] - ws_logit[2 * i + 1];
        out[i] = 1.0f / (1.0f + fexp2(-LOG2E * x));
    }
}

extern "C" void kernel_launch(void* const* d_in, const int* in_sizes, int n_in,
                              void* d_out, int out_size, void* d_ws, size_t ws_size,
                              hipStream_t stream) {
    const int*   q1    = (const int*)d_in[0];
    const int*   d1    = (const int*)d_in[1];
    const int*   q2    = (const int*)d_in[2];
    const int*   d2    = (const int*)d_in[3];
    const float* emb   = (const float*)d_in[4];
    const float* mlp_w = (const float*)d_in[5];
    float*       out   = (float*)d_out;

    const int B     = out_size;            // 1024
    const int vocab = in_sizes[4] / 50;    // 100000

    float* ws_logit = (float*)d_ws;                       // 2*B floats = 8192 B
    uint4* wse      = (uint4*)((char*)d_ws + 8192);       // prepped embeddings
    size_t need     = 8192 + (size_t)vocab * 256;

    if (ws_size >= need) {
        knrm_prep_kernel<<<dim3((vocab + 31) / 32), dim3(256), 0, stream>>>(emb, wse, vocab);
        knrm_pass_pre<<<dim3(2 * B), dim3(256), 0, stream>>>(
            q1, d1, q2, d2, wse, mlp_w, ws_logit);
    } else {
        knrm_pass_fb<<<dim3(2 * B), dim3(256), 0, stream>>>(
            q1, d1, q2, d2, emb, mlp_w, ws_logit);
    }
    knrm_final_kernel<<<dim3((B + 255) / 256), dim3(256), 0, stream>>>(ws_logit, out, B);
}

// Round 7
// 73.538 us; speedup vs baseline: 1.1600x; 1.1600x over previous
//
#include <hip/hip_runtime.h>
#include <math.h>

#define LOG2E 1.4426950408889634f

typedef __attribute__((ext_vector_type(8))) short short8;   // 8 bf16 (4 VGPR)
typedef __attribute__((ext_vector_type(4))) float f32x4;    // MFMA C/D
typedef __attribute__((ext_vector_type(2))) float f32x2;    // packed-f32 pair

__device__ __forceinline__ float fexp2(float x) { return __builtin_amdgcn_exp2f(x); }

// async global->LDS, 16B per lane. LDS dest must be wave-uniform base
// (+ lane*16 implicit). Source is per-lane (pre-swizzled).
typedef __attribute__((address_space(1))) const unsigned int gas_u32;
typedef __attribute__((address_space(3))) unsigned int las_u32;
__device__ __forceinline__ void glds16(const uint4* gsrc, uint4* ldst_wavebase)
{
    __builtin_amdgcn_global_load_lds((gas_u32*)gsrc, (las_u32*)ldst_wavebase, 16, 0, 0);
}

// 21 Gaussian kernels for 2 sims -> acc[21] (f32x2), DEFERRED normalization
// (validated R6): g_{9+j}(s) = gc * v^j * e^{-j^2/2}, v = e^{10s+0.5},
// gc = e^{-50(s+0.05)^2}. Accumulate p_j = gc*v^j; apply c_j at the fold.
// Overflow-safe with |s|<=1.1: max intermediate e^49.
__device__ __forceinline__ void kern21(f32x2 s, f32x2* acc)
{
    s.x = __builtin_amdgcn_fmed3f(s.x, -1.1f, 1.1f);
    s.y = __builtin_amdgcn_fmed3f(s.y, -1.1f, 1.1f);

    f32x2 va = s * 14.426950408889634f + 0.7213475204444817f;  // log2(e)*(10s+0.5)
    f32x2 v, vi, gc;
    v.x  = fexp2(va.x);  v.y  = fexp2(va.y);
    vi.x = __builtin_amdgcn_rcpf(v.x);
    vi.y = __builtin_amdgcn_rcpf(v.y);
    f32x2 t9 = s + 0.05f;
    f32x2 ga = (t9 * t9) * -72.13475204444817f;                // -50/ln2
    gc.x = fexp2(ga.x);  gc.y = fexp2(ga.y);

    f32x2 p = gc;
    acc[9] += p;
    #pragma unroll
    for (int k = 10; k <= 19; ++k) { p *= v; acc[k] += p; }    // up: j=1..10
    f32x2 q = gc;
    #pragma unroll
    for (int k = 8; k >= 0; --k) { q *= vi; acc[k] += q; }     // down: j=1..9
    // exact kernel (mu=1, sigma=0.001): wave-uniform skip (~0.1% taken)
    if (__any(fmaxf(s.x, s.y) > 0.995f)) {
        f32x2 te = s - 1.0f;
        f32x2 ea = (te * te) * -721347.5204444817f;
        f32x2 ge; ge.x = fexp2(ea.x); ge.y = fexp2(ea.y);
        acc[20] += ge;
    }
}

// One doc chunk step: 6 MFMAs (hi/lo 3-term split) + 2x kern21.
__device__ __forceinline__ void doc_step(
    short8 Ah0, short8 Ah1, short8 Al0, short8 Al1,
    short8 Bh0, short8 Bh1, short8 Bl0, short8 Bl1, f32x2* acc)
{
    f32x4 C = {0.f, 0.f, 0.f, 0.f};
    C = __builtin_amdgcn_mfma_f32_16x16x32_bf16(Ah0, Bh0, C, 0, 0, 0);
    C = __builtin_amdgcn_mfma_f32_16x16x32_bf16(Ah1, Bh1, C, 0, 0, 0);
    C = __builtin_amdgcn_mfma_f32_16x16x32_bf16(Ah0, Bl0, C, 0, 0, 0);
    C = __builtin_amdgcn_mfma_f32_16x16x32_bf16(Ah1, Bl1, C, 0, 0, 0);
    C = __builtin_amdgcn_mfma_f32_16x16x32_bf16(Al0, Bh0, C, 0, 0, 0);
    C = __builtin_amdgcn_mfma_f32_16x16x32_bf16(Al1, Bh1, C, 0, 0, 0);

    f32x2 a01 = {C[0], C[1]};
    f32x2 a23 = {C[2], C[3]};
    kern21(a01, acc);
    kern21(a23, acc);
}

// ---- prep: normalize + bf16 hi/lo split every vocab row into ws ----
// layout: wse[tok*16 + 0..7] = hi chunks, wse[tok*16 + 8..15] = lo chunks
__global__ __launch_bounds__(256) void knrm_prep_kernel(
    const float* __restrict__ emb, uint4* __restrict__ wse, int vocab)
{
    const int tid = threadIdx.x;
    const int row = blockIdx.x * 32 + (tid >> 3);
    const int cb  = tid & 7;
    if (row >= vocab) return;   // whole 8-lane group exits together

    const float* src = emb + (size_t)row * 50;
    float v[8];
    float ss = 0.f;
    #pragma unroll
    for (int p = 0; p < 4; ++p) {
        int e = cb * 8 + 2 * p;
        float2 t;
        if (e + 2 <= 50) t = *(const float2*)(src + e);
        else             t = make_float2(0.f, 0.f);
        v[2*p]   = t.x;
        v[2*p+1] = t.y;
        ss = fmaf(t.x, t.x, fmaf(t.y, t.y, ss));
    }
    ss += __shfl_xor(ss, 1, 64);
    ss += __shfl_xor(ss, 2, 64);
    ss += __shfl_xor(ss, 4, 64);
    float rn = __builtin_amdgcn_rsqf(ss);

    unsigned hw[4], lw[4];
    #pragma unroll
    for (int p = 0; p < 4; ++p) {
        float a = v[2*p]   * rn;
        float b = v[2*p+1] * rn;
        unsigned ha = __float_as_uint(a) & 0xFFFF0000u;
        unsigned hb = __float_as_uint(b) & 0xFFFF0000u;
        float la = a - __uint_as_float(ha);
        float lb = b - __uint_as_float(hb);
        hw[p] = (ha >> 16) | hb;
        lw[p] = (__float_as_uint(la) >> 16) | (__float_as_uint(lb) & 0xFFFF0000u);
    }
    wse[(size_t)row * 16 + cb]     = make_uint4(hw[0], hw[1], hw[2], hw[3]);
    wse[(size_t)row * 16 + 8 + cb] = make_uint4(lw[0], lw[1], lw[2], lw[3]);
}

__device__ __forceinline__ short8 frag_ld(const uint4* mat, int row, int chunk)
{
    return __builtin_bit_cast(short8, mat[row * 8 + (chunk ^ (row & 7))]);
}

// ==== main pass kernel (PRE): LDS-staged docs, global_load_lds pipeline ====
// One block = one (batch, pass). 4 waves: wave = (qtile<<1)|dtile.
// Doc chunk staging: linear LDS dest (pos = tid) + pre-swizzled global
// source chunk cs = (tid&7)^((tid>>3)&7); reads use the same XOR ->
// involution matches (rule #21). Per row, the 8 lanes' cs values cover a
// contiguous 128B segment of wse -> coalesced. One barrier per chunk;
// glds issued right after the barrier so in-flight = full compute phase.
__global__ __launch_bounds__(256, 4) void knrm_pass_pre(
    const int* __restrict__ q1, const int* __restrict__ d1,
    const int* __restrict__ q2, const int* __restrict__ d2,
    const uint4* __restrict__ wse, const float* __restrict__ mlp_w,
    float* __restrict__ ws_logit)
{
    __shared__ uint4 qh4[256], ql4[256];        // Q: 32 rows x 64 bf16 hi/lo
    __shared__ uint4 dh4[2][256], dl4[2][256];  // docs, double-buffered
    __shared__ float Swk[4][21][16];
    __shared__ float wred[4];

    const int tid  = threadIdx.x;
    const int bx   = blockIdx.x;
    const int b    = bx >> 1;
    const int lane = tid & 63;
    const int wave = tid >> 6;
    const int g    = lane >> 4;          // k-group 0..3

    const int* qidx = ((bx & 1) ? q2 : q1) + b * 32;
    const int* didx = ((bx & 1) ? d2 : d1) + b * 512;

    const int srow = tid >> 3;                   // staging row 0..31
    const int scb  = tid & 7;                    // linear chunk pos 0..7
    const int swz  = scb ^ (srow & 7);           // chunk to fetch for pos tid
    const int wbase = (tid >> 6) * 64;           // wave-uniform LDS base (uint4 idx)

    // ---- prologue: Q (manual, swizzled write) + doc chunk 0 via glds ----
    {
        const uint4* sq = wse + (size_t)qidx[srow] * 16;
        int qpos = srow * 8 + swz;               // fetch chunk swz -> pos tid? no:
        // manual path: fetch chunk scb, write pos srow*8 + (scb^(srow&7)) == tid? 
        // equivalently fetch chunk swz and write pos tid (linear). Use linear:
        qh4[tid] = sq[swz];
        ql4[tid] = sq[8 + swz];
        (void)qpos;
        const uint4* a0 = wse + (size_t)didx[srow] * 16;
        glds16(a0 + swz,     &dh4[0][wbase]);
        glds16(a0 + 8 + swz, &dl4[0][wbase]);
    }
    int tokN = didx[32 + srow];
    __syncthreads();

    // ---- B-operand fragments (fixed for the whole pass) ----
    const int qrow = (wave >> 1) * 16 + (lane & 15);
    short8 Bh0 = frag_ld(qh4, qrow, g);
    short8 Bh1 = frag_ld(qh4, qrow, 4 + g);
    short8 Bl0 = frag_ld(ql4, qrow, g);
    short8 Bl1 = frag_ld(ql4, qrow, 4 + g);

    f32x2 acc2[21];
    #pragma unroll
    for (int k = 0; k < 21; ++k) acc2[k] = (f32x2){0.f, 0.f};

    const int arow = (wave & 1) * 16 + (lane & 15);

    #pragma unroll 2
    for (int c = 0; c < 16; ++c) {
        // 1) issue next chunk's async staging (right after the barrier)
        if (c < 15) {
            const uint4* an = wse + (size_t)tokN * 16;
            glds16(an + swz,     &dh4[(c + 1) & 1][wbase]);
            glds16(an + 8 + swz, &dl4[(c + 1) & 1][wbase]);
            if (c < 14) tokN = didx[(c + 2) * 32 + srow];
        }
        // 2) compute current chunk from buf[c&1]
        const uint4* dhb = dh4[c & 1];
        const uint4* dlb = dl4[c & 1];
        short8 Ah0 = frag_ld(dhb, arow, g);
        short8 Ah1 = frag_ld(dhb, arow, 4 + g);
        short8 Al0 = frag_ld(dlb, arow, g);
        short8 Al1 = frag_ld(dlb, arow, 4 + g);
        doc_step(Ah0, Ah1, Al0, Al1, Bh0, Bh1, Bl0, Bl1, acc2);

        // 3) barrier: drains glds (vmcnt) + syncs buffer handoff
        __syncthreads();
    }

    // ---- fold packed pair, then the 4 doc-row groups ----
    float acc[21];
    #pragma unroll
    for (int k = 0; k < 21; ++k) {
        float v = acc2[k].x + acc2[k].y;
        v += __shfl_xor(v, 16, 64);
        v += __shfl_xor(v, 32, 64);
        acc[k] = v;
    }
    if (lane < 16) {
        #pragma unroll
        for (int k = 0; k < 21; ++k) Swk[wave][k][lane] = acc[k];
    }
    __syncthreads();

    // ---- log1p + deferred c_j scale + kernel weights + block reduction ----
    float local = 0.f;
    for (int p = tid; p < 21 * 32; p += 256) {
        int k = p >> 5, q = p & 31;
        int wp = (q >> 4) * 2;
        float S = Swk[wp][k][q & 15] + Swk[wp + 1][k][q & 15];
        float j = (float)(k - 9);
        float scale = (k < 20) ? fexp2(-0.7213475204444817f * j * j) : 1.0f;
        local += mlp_w[k] * log1pf(S * scale);
    }
    #pragma unroll
    for (int off = 1; off < 64; off <<= 1) local += __shfl_xor(local, off, 64);
    if (lane == 0) wred[wave] = local;
    __syncthreads();
    if (tid == 0)
        ws_logit[bx] = wred[0] + wred[1] + wred[2] + wred[3];  // bias cancels in l1-l2
}

// ==== fallback (ws too small): R2-proven in-kernel staging via LDS ====
__device__ __forceinline__ void stage_row_chunk(
    const float* __restrict__ emb, int tok, int row, int cb,
    uint4* __restrict__ hmat, uint4* __restrict__ lmat)
{
    const float* src = emb + (size_t)tok * 50;
    float v[8];
    float ss = 0.f;
    #pragma unroll
    for (int p = 0; p < 4; ++p) {
        int e = cb * 8 + 2 * p;
        float2 t;
        if (e + 2 <= 50) t = *(const float2*)(src + e);
        else             t = make_float2(0.f, 0.f);
        v[2*p]   = t.x;
        v[2*p+1] = t.y;
        ss = fmaf(t.x, t.x, fmaf(t.y, t.y, ss));
    }
    ss += __shfl_xor(ss, 1, 64);
    ss += __shfl_xor(ss, 2, 64);
    ss += __shfl_xor(ss, 4, 64);
    float rn = __builtin_amdgcn_rsqf(ss);

    unsigned hw[4], lw[4];
    #pragma unroll
    for (int p = 0; p < 4; ++p) {
        float a = v[2*p]   * rn;
        float b = v[2*p+1] * rn;
        unsigned ha = __float_as_uint(a) & 0xFFFF0000u;
        unsigned hb = __float_as_uint(b) & 0xFFFF0000u;
        float la = a - __uint_as_float(ha);
        float lb = b - __uint_as_float(hb);
        hw[p] = (ha >> 16) | hb;
        lw[p] = (__float_as_uint(la) >> 16) | (__float_as_uint(lb) & 0xFFFF0000u);
    }
    int cidx = cb ^ (row & 7);
    hmat[row * 8 + cidx] = make_uint4(hw[0], hw[1], hw[2], hw[3]);
    lmat[row * 8 + cidx] = make_uint4(lw[0], lw[1], lw[2], lw[3]);
}

__global__ __launch_bounds__(256, 4) void knrm_pass_fb(
    const int* __restrict__ q1, const int* __restrict__ d1,
    const int* __restrict__ q2, const int* __restrict__ d2,
    const float* __restrict__ emb, const float* __restrict__ mlp_w,
    float* __restrict__ ws_logit)
{
    __shared__ uint4 qh4[256], ql4[256];
    __shared__ uint4 dh4[256], dl4[256];
    __shared__ float Swk[4][21][16];
    __shared__ float wred[4];

    const int tid  = threadIdx.x;
    const int bx   = blockIdx.x;
    const int b    = bx >> 1;
    const int lane = tid & 63;
    const int wave = tid >> 6;
    const int g    = lane >> 4;

    const int* qidx = ((bx & 1) ? q2 : q1) + b * 32;
    const int* didx = ((bx & 1) ? d2 : d1) + b * 512;

    const int srow = tid >> 3;
    const int scb  = tid & 7;

    stage_row_chunk(emb, qidx[srow], srow, scb, qh4, ql4);
    __syncthreads();

    const int qrow = (wave >> 1) * 16 + (lane & 15);
    short8 Bh0 = frag_ld(qh4, qrow, g);
    short8 Bh1 = frag_ld(qh4, qrow, 4 + g);
    short8 Bl0 = frag_ld(ql4, qrow, g);
    short8 Bl1 = frag_ld(ql4, qrow, 4 + g);

    f32x2 acc2[21];
    #pragma unroll
    for (int k = 0; k < 21; ++k) acc2[k] = (f32x2){0.f, 0.f};

    const int arow = (wave & 1) * 16 + (lane & 15);

    for (int c = 0; c < 16; ++c) {
        if (c) __syncthreads();
        stage_row_chunk(emb, didx[c * 32 + srow], srow, scb, dh4, dl4);
        __syncthreads();

        short8 Ah0 = frag_ld(dh4, arow, g);
        short8 Ah1 = frag_ld(dh4, arow, 4 + g);
        short8 Al0 = frag_ld(dl4, arow, g);
        short8 Al1 = frag_ld(dl4, arow, 4 + g);
        doc_step(Ah0, Ah1, Al0, Al1, Bh0, Bh1, Bl0, Bl1, acc2);
    }
    __syncthreads();

    float acc[21];
    #pragma unroll
    for (int k = 0; k < 21; ++k) {
        float v = acc2[k].x + acc2[k].y;
        v += __shfl_xor(v, 16, 64);
        v += __shfl_xor(v, 32, 64);
        acc[k] = v;
    }
    if (lane < 16) {
        #pragma unroll
        for (int k = 0; k < 21; ++k) Swk[wave][k][lane] = acc[k];
    }
    __syncthreads();

    float local = 0.f;
    for (int p = tid; p < 21 * 32; p += 256) {
        int k = p >> 5, q = p & 31;
        int wp = (q >> 4) * 2;
        float S = Swk[wp][k][q & 15] + Swk[wp + 1][k][q & 15];
        float j = (float)(k - 9);
        float scale = (k < 20) ? fexp2(-0.7213475204444817f * j * j) : 1.0f;
        local += mlp_w[k] * log1pf(S * scale);
    }
    #pragma unroll
    for (int off = 1; off < 64; off <<= 1) local += __shfl_xor(local, off, 64);
    if (lane == 0) wred[wave] = local;
    __syncthreads();
    if (tid == 0)
        ws_logit[bx] = wred[0] + wred[1] + wred[2] + wred[3];
}

__global__ void knrm_final_kernel(const float* __restrict__ ws_logit,
                                  float* __restrict__ out, int B)
{
    int i = blockIdx.x * 256 + threadIdx.x;
    if (i < B) {
        float x = ws_logit[2 * i] - ws_logit[2 * i + 1];
        out[i] = 1.0f / (1.0f + fexp2(-LOG2E * x));
    }
}

extern "C" void kernel_launch(void* const* d_in, const int* in_sizes, int n_in,
                              void* d_out, int out_size, void* d_ws, size_t ws_size,
                              hipStream_t stream) {
    const int*   q1    = (const int*)d_in[0];
    const int*   d1    = (const int*)d_in[1];
    const int*   q2    = (const int*)d_in[2];
    const int*   d2    = (const int*)d_in[3];
    const float* emb   = (const float*)d_in[4];
    const float* mlp_w = (const float*)d_in[5];
    float*       out   = (float*)d_out;

    const int B     = out_size;            // 1024
    const int vocab = in_sizes[4] / 50;    // 100000

    float* ws_logit = (float*)d_ws;                       // 2*B floats = 8192 B
    uint4* wse      = (uint4*)((char*)d_ws + 8192);       // prepped embeddings
    size_t need     = 8192 + (size_t)vocab * 256;

    if (ws_size >= need) {
        knrm_prep_kernel<<<dim3((vocab + 31) / 32), dim3(256), 0, stream>>>(emb, wse, vocab);
        knrm_pass_pre<<<dim3(2 * B), dim3(256), 0, stream>>>(
            q1, d1, q2, d2, wse, mlp_w, ws_logit);
    } else {
        knrm_pass_fb<<<dim3(2 * B), dim3(256), 0, stream>>>(
            q1, d1, q2, d2, emb, mlp_w, ws_logit);
    }
    knrm_final_kernel<<<dim3((B + 255) / 256), dim3(256), 0, stream>>>(ws_logit, out, B);
}

// Round 8
// 72.581 us; speedup vs baseline: 1.1753x; 1.0132x over previous
//
#include <hip/hip_runtime.h>
#include <math.h>

#define LOG2E 1.4426950408889634f

typedef __attribute__((ext_vector_type(8))) short short8;   // 8 bf16 (4 VGPR)
typedef __attribute__((ext_vector_type(4))) float f32x4;    // MFMA C/D
typedef __attribute__((ext_vector_type(2))) float f32x2;    // packed-f32 pair

__device__ __forceinline__ float fexp2(float x) { return __builtin_amdgcn_exp2f(x); }

// async global->LDS, 16B per lane: LDS dest = wave-uniform base + lane*16;
// global source per-lane (pre-swizzled).
typedef __attribute__((address_space(1))) const unsigned int gas_u32;
typedef __attribute__((address_space(3))) unsigned int las_u32;
__device__ __forceinline__ void glds16(const uint4* gsrc, uint4* ldst_wavebase)
{
    __builtin_amdgcn_global_load_lds((gas_u32*)gsrc, (las_u32*)ldst_wavebase, 16, 0, 0);
}

// 21 Gaussian kernels for 2 sims -> acc[21] (f32x2), DEFERRED normalization
// (validated R6/R7): g_{9+j}(s) = gc * v^j * e^{-j^2/2}, v = e^{10s+0.5},
// gc = e^{-50(s+0.05)^2}. Accumulate p_j = gc*v^j; apply c_j at the fold.
// Overflow-safe with |s|<=1.1: max intermediate e^49.
__device__ __forceinline__ void kern21(f32x2 s, f32x2* acc)
{
    s.x = __builtin_amdgcn_fmed3f(s.x, -1.1f, 1.1f);
    s.y = __builtin_amdgcn_fmed3f(s.y, -1.1f, 1.1f);

    f32x2 va = s * 14.426950408889634f + 0.7213475204444817f;  // log2(e)*(10s+0.5)
    f32x2 v, vi, gc;
    v.x  = fexp2(va.x);  v.y  = fexp2(va.y);
    vi.x = __builtin_amdgcn_rcpf(v.x);
    vi.y = __builtin_amdgcn_rcpf(v.y);
    f32x2 t9 = s + 0.05f;
    f32x2 ga = (t9 * t9) * -72.13475204444817f;                // -50/ln2
    gc.x = fexp2(ga.x);  gc.y = fexp2(ga.y);

    f32x2 p = gc;
    acc[9] += p;
    #pragma unroll
    for (int k = 10; k <= 19; ++k) { p *= v; acc[k] += p; }    // up: j=1..10
    f32x2 q = gc;
    #pragma unroll
    for (int k = 8; k >= 0; --k) { q *= vi; acc[k] += q; }     // down: j=1..9
    // exact kernel (mu=1, sigma=0.001): wave-uniform skip (~0.1% taken)
    if (__any(fmaxf(s.x, s.y) > 0.995f)) {
        f32x2 te = s - 1.0f;
        f32x2 ea = (te * te) * -721347.5204444817f;
        f32x2 ge; ge.x = fexp2(ea.x); ge.y = fexp2(ea.y);
        acc[20] += ge;
    }
}

// One doc tile step: 6 MFMAs (hi/lo 3-term split) + 2x kern21.
__device__ __forceinline__ void doc_step(
    short8 Ah0, short8 Ah1, short8 Al0, short8 Al1,
    short8 Bh0, short8 Bh1, short8 Bl0, short8 Bl1, f32x2* acc)
{
    f32x4 C = {0.f, 0.f, 0.f, 0.f};
    C = __builtin_amdgcn_mfma_f32_16x16x32_bf16(Ah0, Bh0, C, 0, 0, 0);
    C = __builtin_amdgcn_mfma_f32_16x16x32_bf16(Ah1, Bh1, C, 0, 0, 0);
    C = __builtin_amdgcn_mfma_f32_16x16x32_bf16(Ah0, Bl0, C, 0, 0, 0);
    C = __builtin_amdgcn_mfma_f32_16x16x32_bf16(Ah1, Bl1, C, 0, 0, 0);
    C = __builtin_amdgcn_mfma_f32_16x16x32_bf16(Al0, Bh0, C, 0, 0, 0);
    C = __builtin_amdgcn_mfma_f32_16x16x32_bf16(Al1, Bh1, C, 0, 0, 0);

    f32x2 a01 = {C[0], C[1]};
    f32x2 a23 = {C[2], C[3]};
    kern21(a01, acc);
    kern21(a23, acc);
}

// ---- prep: normalize + bf16 hi/lo split every vocab row into ws ----
// layout: wse[tok*16 + 0..7] = hi chunks, wse[tok*16 + 8..15] = lo chunks
__global__ __launch_bounds__(256) void knrm_prep_kernel(
    const float* __restrict__ emb, uint4* __restrict__ wse, int vocab)
{
    const int tid = threadIdx.x;
    const int row = blockIdx.x * 32 + (tid >> 3);
    const int cb  = tid & 7;
    if (row >= vocab) return;   // whole 8-lane group exits together

    const float* src = emb + (size_t)row * 50;
    float v[8];
    float ss = 0.f;
    #pragma unroll
    for (int p = 0; p < 4; ++p) {
        int e = cb * 8 + 2 * p;
        float2 t;
        if (e + 2 <= 50) t = *(const float2*)(src + e);
        else             t = make_float2(0.f, 0.f);
        v[2*p]   = t.x;
        v[2*p+1] = t.y;
        ss = fmaf(t.x, t.x, fmaf(t.y, t.y, ss));
    }
    ss += __shfl_xor(ss, 1, 64);
    ss += __shfl_xor(ss, 2, 64);
    ss += __shfl_xor(ss, 4, 64);
    float rn = __builtin_amdgcn_rsqf(ss);

    unsigned hw[4], lw[4];
    #pragma unroll
    for (int p = 0; p < 4; ++p) {
        float a = v[2*p]   * rn;
        float b = v[2*p+1] * rn;
        unsigned ha = __float_as_uint(a) & 0xFFFF0000u;
        unsigned hb = __float_as_uint(b) & 0xFFFF0000u;
        float la = a - __uint_as_float(ha);
        float lb = b - __uint_as_float(hb);
        hw[p] = (ha >> 16) | hb;
        lw[p] = (__float_as_uint(la) >> 16) | (__float_as_uint(lb) & 0xFFFF0000u);
    }
    wse[(size_t)row * 16 + cb]     = make_uint4(hw[0], hw[1], hw[2], hw[3]);
    wse[(size_t)row * 16 + 8 + cb] = make_uint4(lw[0], lw[1], lw[2], lw[3]);
}

__device__ __forceinline__ short8 frag_ld(const uint4* mat, int row, int chunk)
{
    return __builtin_bit_cast(short8, mat[row * 8 + (chunk ^ (row & 7))]);
}

// ==== main pass kernel (PRE) ====
// One block = one (batch, pass). 4 waves = (qtile in {0,1}) x (dhalf in {0,1}).
// Doc chunk = 64 rows, double-buffered (dbuf[p]: hi rows in [0..512), lo in
// [512..1024) uint4). Q overlays dbuf[1][0..512) during the prologue only
// (dead after B-frags go to registers; barrier #2 protects the overwrite).
// Staging: wave w stages rows [16w,16w+16) via 4 glds, linear LDS dest +
// pre-swizzled global source (chunk = pos ^ (row&7)); frag reads use the
// same XOR involution (rule #21). Per chunk: 2 doc_steps, ONE barrier.
__global__ __launch_bounds__(256, 4) void knrm_pass_pre(
    const int* __restrict__ q1, const int* __restrict__ d1,
    const int* __restrict__ q2, const int* __restrict__ d2,
    const uint4* __restrict__ wse, const float* __restrict__ mlp_w,
    float* __restrict__ ws_logit)
{
    __shared__ uint4 dbuf[2][1024];   // 32 KB
    __shared__ float Swk[4][21][16];
    __shared__ float wred[4];

    const int tid  = threadIdx.x;
    const int bx   = blockIdx.x;
    const int b    = bx >> 1;
    const int lane = tid & 63;
    const int wave = tid >> 6;
    const int g    = lane >> 4;          // k-group 0..3

    const int* qidx = ((bx & 1) ? q2 : q1) + b * 32;
    const int* didx = ((bx & 1) ? d2 : d1) + b * 512;

    const int rsub = lane >> 3;          // 0..7 (staging sub-row)
    const int cpos = lane & 7;           // linear chunk pos in row
    const int swz  = cpos ^ rsub;        // global chunk to fetch for this pos

    // ---- prologue ----
    {   // Q -> dbuf[1] (manual swizzled write): hi [0..256), lo [256..512)
        const int srow = tid >> 3, scb = tid & 7;
        const uint4* sq = wse + (size_t)qidx[srow] * 16;
        int pos = srow * 8 + (scb ^ (srow & 7));
        dbuf[1][pos]       = sq[scb];
        dbuf[1][256 + pos] = sq[8 + scb];
    }
    {   // doc chunk 0 -> dbuf[0] via glds (wave w: rows 16w..16w+16)
        int r0 = wave * 16 + rsub;
        int r1 = r0 + 8;
        const uint4* p0 = wse + (size_t)didx[r0] * 16;
        const uint4* p1 = wse + (size_t)didx[r1] * 16;
        glds16(p0 + swz,     &dbuf[0][wave * 128]);
        glds16(p1 + swz,     &dbuf[0][wave * 128 + 64]);
        glds16(p0 + 8 + swz, &dbuf[0][512 + wave * 128]);
        glds16(p1 + 8 + swz, &dbuf[0][512 + wave * 128 + 64]);
    }
    // token indices for chunk 1 (depth-1 prefetch)
    int tokA = didx[64 + wave * 16 + rsub];
    int tokB = didx[64 + wave * 16 + 8 + rsub];
    __syncthreads();   // Q staged + chunk-0 glds drained

    // ---- B fragments (registers, fixed all pass) from Q region ----
    const int qrow = (wave >> 1) * 16 + (lane & 15);
    short8 Bh0 = frag_ld(dbuf[1], qrow, g);
    short8 Bh1 = frag_ld(dbuf[1], qrow, 4 + g);
    short8 Bl0 = frag_ld(dbuf[1] + 256, qrow, g);
    short8 Bl1 = frag_ld(dbuf[1] + 256, qrow, 4 + g);
    __syncthreads();   // all B reads done before chunk-1 glds overwrites dbuf[1]

    f32x2 acc2[21];
    #pragma unroll
    for (int k = 0; k < 21; ++k) acc2[k] = (f32x2){0.f, 0.f};

    const int dhalf = wave & 1;
    const int ar0 = dhalf * 16 + (lane & 15);   // step-0 row in chunk
    const int ar1 = 32 + ar0;                   // step-1 row in chunk

    for (int c = 0; c < 8; ++c) {
        // 1) issue next chunk's staging right away (in-flight = 2 doc_steps)
        if (c < 7) {
            const uint4* pA = wse + (size_t)tokA * 16;
            const uint4* pB = wse + (size_t)tokB * 16;
            uint4* nb = dbuf[(c + 1) & 1];
            glds16(pA + swz,     nb + wave * 128);
            glds16(pB + swz,     nb + wave * 128 + 64);
            glds16(pA + 8 + swz, nb + 512 + wave * 128);
            glds16(pB + 8 + swz, nb + 512 + wave * 128 + 64);
            if (c < 6) {
                tokA = didx[(c + 2) * 64 + wave * 16 + rsub];
                tokB = didx[(c + 2) * 64 + wave * 16 + 8 + rsub];
            }
        }
        // 2) compute 2 tiles from current buffer
        const uint4* hb = dbuf[c & 1];
        const uint4* lb = dbuf[c & 1] + 512;
        doc_step(frag_ld(hb, ar0, g), frag_ld(hb, ar0, 4 + g),
                 frag_ld(lb, ar0, g), frag_ld(lb, ar0, 4 + g),
                 Bh0, Bh1, Bl0, Bl1, acc2);
        doc_step(frag_ld(hb, ar1, g), frag_ld(hb, ar1, 4 + g),
                 frag_ld(lb, ar1, g), frag_ld(lb, ar1, 4 + g),
                 Bh0, Bh1, Bl0, Bl1, acc2);
        // 3) barrier (drains glds + hands off buffers)
        __syncthreads();
    }

    // ---- fold packed pair, then the 4 doc-row groups ----
    float acc[21];
    #pragma unroll
    for (int k = 0; k < 21; ++k) {
        float v = acc2[k].x + acc2[k].y;
        v += __shfl_xor(v, 16, 64);
        v += __shfl_xor(v, 32, 64);
        acc[k] = v;
    }
    if (lane < 16) {
        #pragma unroll
        for (int k = 0; k < 21; ++k) Swk[wave][k][lane] = acc[k];
    }
    __syncthreads();

    // ---- log1p + deferred c_j scale + kernel weights + block reduction ----
    float local = 0.f;
    for (int p = tid; p < 21 * 32; p += 256) {
        int k = p >> 5, q = p & 31;
        int wp = (q >> 4) * 2;
        float S = Swk[wp][k][q & 15] + Swk[wp + 1][k][q & 15];
        float j = (float)(k - 9);
        float scale = (k < 20) ? fexp2(-0.7213475204444817f * j * j) : 1.0f;
        local += mlp_w[k] * log1pf(S * scale);
    }
    #pragma unroll
    for (int off = 1; off < 64; off <<= 1) local += __shfl_xor(local, off, 64);
    if (lane == 0) wred[wave] = local;
    __syncthreads();
    if (tid == 0)
        ws_logit[bx] = wred[0] + wred[1] + wred[2] + wred[3];  // bias cancels in l1-l2
}

// ==== fallback (ws too small): R2-proven in-kernel staging via LDS ====
__device__ __forceinline__ void stage_row_chunk(
    const float* __restrict__ emb, int tok, int row, int cb,
    uint4* __restrict__ hmat, uint4* __restrict__ lmat)
{
    const float* src = emb + (size_t)tok * 50;
    float v[8];
    float ss = 0.f;
    #pragma unroll
    for (int p = 0; p < 4; ++p) {
        int e = cb * 8 + 2 * p;
        float2 t;
        if (e + 2 <= 50) t = *(const float2*)(src + e);
        else             t = make_float2(0.f, 0.f);
        v[2*p]   = t.x;
        v[2*p+1] = t.y;
        ss = fmaf(t.x, t.x, fmaf(t.y, t.y, ss));
    }
    ss += __shfl_xor(ss, 1, 64);
    ss += __shfl_xor(ss, 2, 64);
    ss += __shfl_xor(ss, 4, 64);
    float rn = __builtin_amdgcn_rsqf(ss);

    unsigned hw[4], lw[4];
    #pragma unroll
    for (int p = 0; p < 4; ++p) {
        float a = v[2*p]   * rn;
        float b = v[2*p+1] * rn;
        unsigned ha = __float_as_uint(a) & 0xFFFF0000u;
        unsigned hb = __float_as_uint(b) & 0xFFFF0000u;
        float la = a - __uint_as_float(ha);
        float lb = b - __uint_as_float(hb);
        hw[p] = (ha >> 16) | hb;
        lw[p] = (__float_as_uint(la) >> 16) | (__float_as_uint(lb) & 0xFFFF0000u);
    }
    int cidx = cb ^ (row & 7);
    hmat[row * 8 + cidx] = make_uint4(hw[0], hw[1], hw[2], hw[3]);
    lmat[row * 8 + cidx] = make_uint4(lw[0], lw[1], lw[2], lw[3]);
}

__global__ __launch_bounds__(256, 4) void knrm_pass_fb(
    const int* __restrict__ q1, const int* __restrict__ d1,
    const int* __restrict__ q2, const int* __restrict__ d2,
    const float* __restrict__ emb, const float* __restrict__ mlp_w,
    float* __restrict__ ws_logit)
{
    __shared__ uint4 qh4[256], ql4[256];
    __shared__ uint4 dh4[256], dl4[256];
    __shared__ float Swk[4][21][16];
    __shared__ float wred[4];

    const int tid  = threadIdx.x;
    const int bx   = blockIdx.x;
    const int b    = bx >> 1;
    const int lane = tid & 63;
    const int wave = tid >> 6;
    const int g    = lane >> 4;

    const int* qidx = ((bx & 1) ? q2 : q1) + b * 32;
    const int* didx = ((bx & 1) ? d2 : d1) + b * 512;

    const int srow = tid >> 3;
    const int scb  = tid & 7;

    stage_row_chunk(emb, qidx[srow], srow, scb, qh4, ql4);
    __syncthreads();

    const int qrow = (wave >> 1) * 16 + (lane & 15);
    short8 Bh0 = frag_ld(qh4, qrow, g);
    short8 Bh1 = frag_ld(qh4, qrow, 4 + g);
    short8 Bl0 = frag_ld(ql4, qrow, g);
    short8 Bl1 = frag_ld(ql4, qrow, 4 + g);

    f32x2 acc2[21];
    #pragma unroll
    for (int k = 0; k < 21; ++k) acc2[k] = (f32x2){0.f, 0.f};

    const int arow = (wave & 1) * 16 + (lane & 15);

    for (int c = 0; c < 16; ++c) {
        if (c) __syncthreads();
        stage_row_chunk(emb, didx[c * 32 + srow], srow, scb, dh4, dl4);
        __syncthreads();

        doc_step(frag_ld(dh4, arow, g), frag_ld(dh4, arow, 4 + g),
                 frag_ld(dl4, arow, g), frag_ld(dl4, arow, 4 + g),
                 Bh0, Bh1, Bl0, Bl1, acc2);
    }
    __syncthreads();

    float acc[21];
    #pragma unroll
    for (int k = 0; k < 21; ++k) {
        float v = acc2[k].x + acc2[k].y;
        v += __shfl_xor(v, 16, 64);
        v += __shfl_xor(v, 32, 64);
        acc[k] = v;
    }
    if (lane < 16) {
        #pragma unroll
        for (int k = 0; k < 21; ++k) Swk[wave][k][lane] = acc[k];
    }
    __syncthreads();

    float local = 0.f;
    for (int p = tid; p < 21 * 32; p += 256) {
        int k = p >> 5, q = p & 31;
        int wp = (q >> 4) * 2;
        float S = Swk[wp][k][q & 15] + Swk[wp + 1][k][q & 15];
        float j = (float)(k - 9);
        float scale = (k < 20) ? fexp2(-0.7213475204444817f * j * j) : 1.0f;
        local += mlp_w[k] * log1pf(S * scale);
    }
    #pragma unroll
    for (int off = 1; off < 64; off <<= 1) local += __shfl_xor(local, off, 64);
    if (lane == 0) wred[wave] = local;
    __syncthreads();
    if (tid == 0)
        ws_logit[bx] = wred[0] + wred[1] + wred[2] + wred[3];
}

__global__ void knrm_final_kernel(const float* __restrict__ ws_logit,
                                  float* __restrict__ out, int B)
{
    int i = blockIdx.x * 256 + threadIdx.x;
    if (i < B) {
        float x = ws_logit[2 * i] - ws_logit[2 * i + 1];
        out[i] = 1.0f / (1.0f + fexp2(-LOG2E * x));
    }
}

extern "C" void kernel_launch(void* const* d_in, const int* in_sizes, int n_in,
                              void* d_out, int out_size, void* d_ws, size_t ws_size,
                              hipStream_t stream) {
    const int*   q1    = (const int*)d_in[0];
    const int*   d1    = (const int*)d_in[1];
    const int*   q2    = (const int*)d_in[2];
    const int*   d2    = (const int*)d_in[3];
    const float* emb   = (const float*)d_in[4];
    const float* mlp_w = (const float*)d_in[5];
    float*       out   = (float*)d_out;

    const int B     = out_size;            // 1024
    const int vocab = in_sizes[4] / 50;    // 100000

    float* ws_logit = (float*)d_ws;                       // 2*B floats = 8192 B
    uint4* wse      = (uint4*)((char*)d_ws + 8192);       // prepped embeddings
    size_t need     = 8192 + (size_t)vocab * 256;

    if (ws_size >= need) {
        knrm_prep_kernel<<<dim3((vocab + 31) / 32), dim3(256), 0, stream>>>(emb, wse, vocab);
        knrm_pass_pre<<<dim3(2 * B), dim3(256), 0, stream>>>(
            q1, d1, q2, d2, wse, mlp_w, ws_logit);
    } else {
        knrm_pass_fb<<<dim3(2 * B), dim3(256), 0, stream>>>(
            q1, d1, q2, d2, emb, mlp_w, ws_logit);
    }
    knrm_final_kernel<<<dim3((B + 255) / 256), dim3(256), 0, stream>>>(ws_logit, out, B);
}